// Round 1
// baseline (3209.440 us; speedup 1.0000x reference)
//
#include <hip/hip_runtime.h>

#define N_NODES 100000
#define N_EDGES 1600000
#define D_IN    256
#define D_OUT   128

// ---------------------------------------------------------------------------
// GEMM: support[n][j] = sum_k X[n][k] * W[k][j]
// Block = 128 threads: 32 column-groups (4 cols each, float4) x 4 nodes.
// X rows staged in LDS (broadcast reads); W read as coalesced float4.
// 100000 / 4 = 25000 blocks, no tail.
// ---------------------------------------------------------------------------
__global__ __launch_bounds__(128) void gcn_gemm_kernel(
    const float* __restrict__ X,
    const float* __restrict__ W,
    float* __restrict__ support)
{
    __shared__ float xs[4][D_IN];   // 4 KiB

    const int c = threadIdx.x & 31;   // column group: cols [4c, 4c+4)
    const int r = threadIdx.x >> 5;   // node within block: 0..3
    const int node0 = blockIdx.x * 4;

    // Stage 4 rows of X: 4*256 floats = 256 float4s; 128 threads -> 2 each.
    {
        const float4* X4 = (const float4*)(X + (size_t)node0 * D_IN);
        float4* xs4 = (float4*)&xs[0][0];
        xs4[threadIdx.x]       = X4[threadIdx.x];
        xs4[threadIdx.x + 128] = X4[threadIdx.x + 128];
    }
    __syncthreads();

    const float4* W4 = (const float4*)W;  // W row k = 32 float4s
    float4 acc = make_float4(0.f, 0.f, 0.f, 0.f);

#pragma unroll 8
    for (int k = 0; k < D_IN; ++k) {
        const float xv = xs[r][k];              // broadcast within 32-lane group
        const float4 w = W4[k * 32 + c];        // coalesced, L1/L2-resident (128 KiB)
        acc.x = fmaf(xv, w.x, acc.x);
        acc.y = fmaf(xv, w.y, acc.y);
        acc.z = fmaf(xv, w.z, acc.z);
        acc.w = fmaf(xv, w.w, acc.w);
    }

    float4* S4 = (float4*)support;
    S4[(size_t)(node0 + r) * 32 + c] = acc;
}

// ---------------------------------------------------------------------------
// SpMM scatter: out[row[e]] += val[e] * support[col[e]]
// 32 threads per edge, each owns 4 columns (float4 gather, 4 scalar atomics).
// support (51.2 MB) is L3-resident -> gathers mostly cache hits.
// ---------------------------------------------------------------------------
__global__ __launch_bounds__(256) void gcn_spmm_kernel(
    const int*   __restrict__ rows,
    const int*   __restrict__ cols,
    const float* __restrict__ vals,
    const float* __restrict__ support,
    float* __restrict__ out)
{
    const int idx = blockIdx.x * 256 + threadIdx.x;
    const int e = idx >> 5;
    if (e >= N_EDGES) return;
    const int c = idx & 31;

    const int   row = rows[e];
    const int   col = cols[e];
    const float v   = vals[e];

    const float4 s = ((const float4*)support)[(size_t)col * 32 + c];
    float* o = out + (size_t)row * D_OUT + c * 4;
    atomicAdd(o + 0, v * s.x);
    atomicAdd(o + 1, v * s.y);
    atomicAdd(o + 2, v * s.z);
    atomicAdd(o + 3, v * s.w);
}

// ---------------------------------------------------------------------------
// Fused ReLU (in-place), vectorized float4, grid-stride.
// ---------------------------------------------------------------------------
__global__ __launch_bounds__(256) void gcn_relu_kernel(float* __restrict__ out, int n4)
{
    float4* p = (float4*)out;
    for (int i = blockIdx.x * 256 + threadIdx.x; i < n4; i += gridDim.x * 256) {
        float4 v = p[i];
        v.x = v.x > 0.f ? v.x : 0.f;
        v.y = v.y > 0.f ? v.y : 0.f;
        v.z = v.z > 0.f ? v.z : 0.f;
        v.w = v.w > 0.f ? v.w : 0.f;
        p[i] = v;
    }
}

extern "C" void kernel_launch(void* const* d_in, const int* in_sizes, int n_in,
                              void* d_out, int out_size, void* d_ws, size_t ws_size,
                              hipStream_t stream)
{
    const float* X    = (const float*)d_in[0];   // [N_NODES, D_IN]
    const float* W    = (const float*)d_in[1];   // [D_IN, D_OUT]
    const int*   rows = (const int*)  d_in[2];   // [N_EDGES]
    const int*   cols = (const int*)  d_in[3];   // [N_EDGES]
    const float* vals = (const float*)d_in[4];   // [N_EDGES]
    float* out     = (float*)d_out;              // [N_NODES, D_OUT]
    float* support = (float*)d_ws;               // needs N_NODES*D_OUT*4 = 51.2 MB

    // Zero-init output (harness poisons with 0xAA; atomics accumulate into it).
    hipMemsetAsync(d_out, 0, (size_t)out_size * sizeof(float), stream);

    // 1) support = X @ W
    gcn_gemm_kernel<<<N_NODES / 4, 128, 0, stream>>>(X, W, support);

    // 2) out[row] += val * support[col]   (atomic scatter)
    const int spmm_blocks = (N_EDGES * 32 + 255) / 256;  // 200000
    gcn_spmm_kernel<<<spmm_blocks, 256, 0, stream>>>(rows, cols, vals, support, out);

    // 3) ReLU in place
    const int n4 = out_size / 4;
    gcn_relu_kernel<<<2048, 256, 0, stream>>>(out, n4);
}

// Round 2
// 579.401 us; speedup vs baseline: 5.5392x; 5.5392x over previous
//
#include <hip/hip_runtime.h>

#define N_NODES 100000
#define N_EDGES 1600000
#define D_IN    256
#define D_OUT   128

// ---------------------------------------------------------------------------
// GEMM: support = X @ W.  128 threads: 32 col-groups (float4) x 4 row-groups;
// each thread computes 8 rows x 4 cols => 32 rows/block, 3125 blocks.
// X rows staged in LDS (32 KB, coalesced writes, broadcast reads).
// W read as float4 from L2 (128 KB, resident), reused across 8 rows.
// ---------------------------------------------------------------------------
__global__ __launch_bounds__(128) void gcn_gemm_kernel(
    const float* __restrict__ X,
    const float* __restrict__ W,
    float* __restrict__ support)
{
    __shared__ float xs[32][D_IN];   // 32 KiB

    const int tid = threadIdx.x;
    const int c = tid & 31;          // column group: cols [4c, 4c+4)
    const int r = tid >> 5;          // row group: rows [8r, 8r+8)
    const int node0 = blockIdx.x * 32;

    // Stage 32 rows: 32*256 floats = 2048 float4; 16 per thread, coalesced.
    {
        const float4* X4 = (const float4*)(X + (size_t)node0 * D_IN);
        float4* xs4 = (float4*)&xs[0][0];
#pragma unroll
        for (int i = 0; i < 16; ++i) {
            int L = i * 128 + tid;
            xs4[L] = X4[L];
        }
    }
    __syncthreads();

    const float4* W4 = (const float4*)W;
    float4 acc[8];
#pragma unroll
    for (int i = 0; i < 8; ++i) acc[i] = make_float4(0.f, 0.f, 0.f, 0.f);

#pragma unroll 4
    for (int k = 0; k < D_IN; ++k) {
        const float4 w = W4[k * 32 + c];
#pragma unroll
        for (int rr = 0; rr < 8; ++rr) {
            const float xv = xs[r * 8 + rr][k];   // LDS broadcast
            acc[rr].x = fmaf(xv, w.x, acc[rr].x);
            acc[rr].y = fmaf(xv, w.y, acc[rr].y);
            acc[rr].z = fmaf(xv, w.z, acc[rr].z);
            acc[rr].w = fmaf(xv, w.w, acc[rr].w);
        }
    }

    float4* S4 = (float4*)support;
#pragma unroll
    for (int rr = 0; rr < 8; ++rr)
        S4[(size_t)(node0 + r * 8 + rr) * 32 + c] = acc[rr];
}

// ---------------------------------------------------------------------------
// CSR build step 1: histogram of edge rows (int atomics, cheap).
// ---------------------------------------------------------------------------
__global__ __launch_bounds__(256) void gcn_hist_kernel(
    const int* __restrict__ rows, int* __restrict__ counts)
{
    int e = blockIdx.x * 256 + threadIdx.x;
    if (e < N_EDGES) atomicAdd(&counts[rows[e]], 1);
}

// ---------------------------------------------------------------------------
// CSR build step 2a: per-block exclusive scan (1024 elems/block) + block sums.
// ---------------------------------------------------------------------------
__global__ __launch_bounds__(256) void gcn_scan1_kernel(
    const int* __restrict__ counts, int* __restrict__ off, int* __restrict__ bsums)
{
    __shared__ int t[256];
    const int tid = threadIdx.x;
    const int i0 = blockIdx.x * 1024 + tid * 4;

    int c0 = 0, c1 = 0, c2 = 0, c3 = 0;
    if (i0 + 3 < N_NODES) {
        int4 v = *(const int4*)&counts[i0];
        c0 = v.x; c1 = v.y; c2 = v.z; c3 = v.w;
    } else {
        if (i0 + 0 < N_NODES) c0 = counts[i0 + 0];
        if (i0 + 1 < N_NODES) c1 = counts[i0 + 1];
        if (i0 + 2 < N_NODES) c2 = counts[i0 + 2];
        if (i0 + 3 < N_NODES) c3 = counts[i0 + 3];
    }
    const int s = c0 + c1 + c2 + c3;
    t[tid] = s;
    __syncthreads();

    // Hillis-Steele inclusive scan over 256 per-thread sums.
    for (int d = 1; d < 256; d <<= 1) {
        int x = t[tid];
        int add = (tid >= d) ? t[tid - d] : 0;
        __syncthreads();
        t[tid] = x + add;
        __syncthreads();
    }
    const int excl = t[tid] - s;
    if (tid == 255) bsums[blockIdx.x] = t[255];

    const int e0 = excl;
    const int e1 = e0 + c0;
    const int e2 = e1 + c1;
    const int e3 = e2 + c2;
    if (i0 + 0 < N_NODES) off[i0 + 0] = e0;
    if (i0 + 1 < N_NODES) off[i0 + 1] = e1;
    if (i0 + 2 < N_NODES) off[i0 + 2] = e2;
    if (i0 + 3 < N_NODES) off[i0 + 3] = e3;
}

// ---------------------------------------------------------------------------
// CSR build step 2b: exclusive scan of the block sums (single block).
// ---------------------------------------------------------------------------
__global__ __launch_bounds__(128) void gcn_scan2_kernel(int* __restrict__ bsums, int nb)
{
    __shared__ int t[128];
    const int tid = threadIdx.x;
    const int v = (tid < nb) ? bsums[tid] : 0;
    t[tid] = v;
    __syncthreads();
    for (int d = 1; d < 128; d <<= 1) {
        int x = t[tid];
        int add = (tid >= d) ? t[tid - d] : 0;
        __syncthreads();
        t[tid] = x + add;
        __syncthreads();
    }
    if (tid < nb) bsums[tid] = t[tid] - v;
}

// ---------------------------------------------------------------------------
// CSR build step 2c: add block offsets; init cursor = start offset.
// ---------------------------------------------------------------------------
__global__ __launch_bounds__(256) void gcn_scan3_kernel(
    const int* __restrict__ bsums, int* __restrict__ off, int* __restrict__ cursor)
{
    int i = blockIdx.x * 256 + threadIdx.x;
    if (i < N_NODES) {
        int o = off[i] + bsums[i >> 10];
        off[i] = o;
        cursor[i] = o;
    }
}

// ---------------------------------------------------------------------------
// CSR build step 3: scatter edges into row-sorted order as (col, val) pairs.
// ---------------------------------------------------------------------------
__global__ __launch_bounds__(256) void gcn_scatter_kernel(
    const int* __restrict__ rows, const int* __restrict__ cols,
    const float* __restrict__ vals, int* __restrict__ cursor,
    int2* __restrict__ edges)
{
    int e = blockIdx.x * 256 + threadIdx.x;
    if (e < N_EDGES) {
        int pos = atomicAdd(&cursor[rows[e]], 1);
        edges[pos] = make_int2(cols[e], __float_as_int(vals[e]));
    }
}

// ---------------------------------------------------------------------------
// Aggregate + ReLU: one 64-lane wave per node, float2 per lane.
// Edges prefetched 64-at-a-time (coalesced), broadcast via __shfl.
// Gathers of support rows are 512B coalesced, L3-resident.
// ---------------------------------------------------------------------------
__global__ __launch_bounds__(256) void gcn_aggregate_kernel(
    const int* __restrict__ off, const int* __restrict__ ends,
    const int2* __restrict__ edges, const float* __restrict__ support,
    float* __restrict__ out)
{
    const int node = blockIdx.x * 4 + (threadIdx.x >> 6);
    if (node >= N_NODES) return;
    const int lane = threadIdx.x & 63;

    const int start = off[node];
    const int end   = ends[node];   // cursor after scatter == segment end

    const float2* S2 = (const float2*)support;
    float2 acc = make_float2(0.f, 0.f);

    for (int base = start; base < end; base += 64) {
        int m = end - base;
        if (m > 64) m = 64;
        int2 e = edges[base + (lane < m ? lane : 0)];
        for (int j = 0; j < m; ++j) {
            const int   col = __shfl(e.x, j);
            const float v   = __int_as_float(__shfl(e.y, j));
            const float2 s  = S2[(size_t)col * 64 + lane];
            acc.x = fmaf(v, s.x, acc.x);
            acc.y = fmaf(v, s.y, acc.y);
        }
    }

    float2 o;
    o.x = acc.x > 0.f ? acc.x : 0.f;
    o.y = acc.y > 0.f ? acc.y : 0.f;
    ((float2*)out)[(size_t)node * 64 + lane] = o;
}

extern "C" void kernel_launch(void* const* d_in, const int* in_sizes, int n_in,
                              void* d_out, int out_size, void* d_ws, size_t ws_size,
                              hipStream_t stream)
{
    const float* X    = (const float*)d_in[0];   // [N_NODES, D_IN]
    const float* W    = (const float*)d_in[1];   // [D_IN, D_OUT]
    const int*   rows = (const int*)  d_in[2];   // [N_EDGES]
    const int*   cols = (const int*)  d_in[3];   // [N_EDGES]
    const float* vals = (const float*)d_in[4];   // [N_EDGES]
    float* out = (float*)d_out;                  // [N_NODES, D_OUT]

    // ---- workspace layout (all 16B aligned) ----
    char* ws = (char*)d_ws;
    size_t p = 0;
    float* support = (float*)(ws + p); p += (size_t)N_NODES * D_OUT * 4;  // 51.2 MB
    int*   counts  = (int*)  (ws + p); p += (size_t)N_NODES * 4;          // 0.4 MB
    int*   off     = (int*)  (ws + p); p += (size_t)N_NODES * 4;          // 0.4 MB
    int*   cursor  = (int*)  (ws + p); p += (size_t)N_NODES * 4;          // 0.4 MB
    int*   bsums   = (int*)  (ws + p); p += 512;
    int2*  edges   = (int2*) (ws + p); p += (size_t)N_EDGES * 8;          // 12.8 MB
    // total ~65.3 MB
    (void)ws_size;

    const int NB = (N_NODES + 1023) / 1024;  // 98 scan blocks

    // 1) support = X @ W   (independent of CSR build)
    gcn_gemm_kernel<<<N_NODES / 32, 128, 0, stream>>>(X, W, support);

    // 2) CSR build
    hipMemsetAsync(counts, 0, (size_t)N_NODES * 4, stream);
    gcn_hist_kernel<<<(N_EDGES + 255) / 256, 256, 0, stream>>>(rows, counts);
    gcn_scan1_kernel<<<NB, 256, 0, stream>>>(counts, off, bsums);
    gcn_scan2_kernel<<<1, 128, 0, stream>>>(bsums, NB);
    gcn_scan3_kernel<<<(N_NODES + 255) / 256, 256, 0, stream>>>(bsums, off, cursor);
    gcn_scatter_kernel<<<(N_EDGES + 255) / 256, 256, 0, stream>>>(rows, cols, vals, cursor, edges);

    // 3) out = ReLU(A @ support)   — gather-reduce, no fp atomics
    gcn_aggregate_kernel<<<(N_NODES + 3) / 4, 256, 0, stream>>>(
        off, cursor, edges, support, out);
}

// Round 4
// 480.376 us; speedup vs baseline: 6.6811x; 1.2061x over previous
//
#include <hip/hip_runtime.h>

#define N_NODES 100000
#define N_EDGES 1600000
#define D_IN    256
#define D_OUT   128

typedef __attribute__((ext_vector_type(8))) short short8;   // 8 bf16 (4 VGPRs)
typedef __attribute__((ext_vector_type(4))) float floatx4;  // MFMA C/D frag

static __device__ __forceinline__ ushort f2bf(float f) {
    union { float f; unsigned u; } v; v.f = f;
    unsigned r = v.u + 0x7fffu + ((v.u >> 16) & 1u);   // RNE truncate to bf16
    return (ushort)(r >> 16);
}

// ---------------------------------------------------------------------------
// GEMM: support(bf16) = X @ W via mfma_f32_16x16x32_bf16.
// Block = 256 thr = 4 waves; 128 rows/block; each wave owns 32 rows x 128 cols.
// W staged once per block into LDS, packed [kg=k/8][col][k%8] bf16 (64 KB) so a
// B-frag for (kg, col-range) is one conflict-free ds_read_b128.
// A-frags read directly from global fp32 (16 rows x 128 B contiguous per step),
// converted to bf16 in-register.
// ---------------------------------------------------------------------------
__global__ __launch_bounds__(256) void gcn_gemm_mfma(
    const float* __restrict__ X,
    const float* __restrict__ W,
    ushort* __restrict__ supp)
{
    __shared__ ushort wp[32 * 128 * 8];   // 64 KiB packed bf16 W

    const int tid  = threadIdx.x;
    const int lane = tid & 63;
    const int wid  = tid >> 6;            // wave 0..3
    const int node0 = blockIdx.x * 128;

    // ---- stage W: pair p=(kg,col); coalesced global reads, linear b128 writes
#pragma unroll
    for (int i = 0; i < 16; ++i) {
        const int p   = i * 256 + tid;     // 4096 pairs
        const int kg  = p >> 7;            // 0..31
        const int col = p & 127;
        const float* wsrc = W + (size_t)(kg * 8) * D_OUT + col;
        short8 v;
#pragma unroll
        for (int ki = 0; ki < 8; ++ki)
            v[ki] = (short)f2bf(wsrc[(size_t)ki * D_OUT]);
        *(short8*)&wp[(size_t)p * 8] = v;
    }
    __syncthreads();

    const int r0    = node0 + wid * 32;            // wave's 32 rows
    const int g     = lane >> 4;                   // k-group 0..3
    const int arow0 = r0 + (lane & 15);
    const int arow1 = arow0 + 16;
    const int crow0 = arow0 < N_NODES - 1 ? arow0 : N_NODES - 1;
    const int crow1 = arow1 < N_NODES - 1 ? arow1 : N_NODES - 1;

    const float* xp0 = X + (size_t)crow0 * D_IN + g * 8;
    const float* xp1 = X + (size_t)crow1 * D_IN + g * 8;

    floatx4 acc[2][8];
#pragma unroll
    for (int t = 0; t < 2; ++t)
#pragma unroll
        for (int n = 0; n < 8; ++n)
            acc[t][n] = (floatx4){0.f, 0.f, 0.f, 0.f};

#pragma unroll
    for (int ks = 0; ks < 8; ++ks) {               // K = 8 x 32
        const float4 u0 = *(const float4*)(xp0 + ks * 32);
        const float4 u1 = *(const float4*)(xp0 + ks * 32 + 4);
        const float4 u2 = *(const float4*)(xp1 + ks * 32);
        const float4 u3 = *(const float4*)(xp1 + ks * 32 + 4);
        short8 a0, a1;
        a0[0] = (short)f2bf(u0.x); a0[1] = (short)f2bf(u0.y);
        a0[2] = (short)f2bf(u0.z); a0[3] = (short)f2bf(u0.w);
        a0[4] = (short)f2bf(u1.x); a0[5] = (short)f2bf(u1.y);
        a0[6] = (short)f2bf(u1.z); a0[7] = (short)f2bf(u1.w);
        a1[0] = (short)f2bf(u2.x); a1[1] = (short)f2bf(u2.y);
        a1[2] = (short)f2bf(u2.z); a1[3] = (short)f2bf(u2.w);
        a1[4] = (short)f2bf(u3.x); a1[5] = (short)f2bf(u3.y);
        a1[6] = (short)f2bf(u3.z); a1[7] = (short)f2bf(u3.w);

        const int kg = ks * 4 + g;
#pragma unroll
        for (int n = 0; n < 8; ++n) {
            const short8 b = *(const short8*)&wp[(size_t)((kg << 7) + n * 16 + (lane & 15)) * 8];
            acc[0][n] = __builtin_amdgcn_mfma_f32_16x16x32_bf16(a0, b, acc[0][n], 0, 0, 0);
            acc[1][n] = __builtin_amdgcn_mfma_f32_16x16x32_bf16(a1, b, acc[1][n], 0, 0, 0);
        }
    }

    // epilogue: C/D layout col=lane&15, row=(lane>>4)*4+i  [m89-verified]
#pragma unroll
    for (int t = 0; t < 2; ++t) {
        const int rbase = r0 + t * 16 + (lane >> 4) * 4;
#pragma unroll
        for (int n = 0; n < 8; ++n) {
            const int col = n * 16 + (lane & 15);
#pragma unroll
            for (int i = 0; i < 4; ++i) {
                const int row = rbase + i;
                if (row < N_NODES)
                    supp[(size_t)row * D_OUT + col] = f2bf(acc[t][n][i]);
            }
        }
    }
}

// ---------------------------------------------------------------------------
// CSR build step 1: histogram of edge rows (int atomics, cheap).
// ---------------------------------------------------------------------------
__global__ __launch_bounds__(256) void gcn_hist_kernel(
    const int* __restrict__ rows, int* __restrict__ counts)
{
    int e = blockIdx.x * 256 + threadIdx.x;
    if (e < N_EDGES) atomicAdd(&counts[rows[e]], 1);
}

// ---------------------------------------------------------------------------
// CSR build step 2a: per-block exclusive scan (1024 elems/block) + block sums.
// ---------------------------------------------------------------------------
__global__ __launch_bounds__(256) void gcn_scan1_kernel(
    const int* __restrict__ counts, int* __restrict__ off, int* __restrict__ bsums)
{
    __shared__ int t[256];
    const int tid = threadIdx.x;
    const int i0 = blockIdx.x * 1024 + tid * 4;

    int c0 = 0, c1 = 0, c2 = 0, c3 = 0;
    if (i0 + 3 < N_NODES) {
        int4 v = *(const int4*)&counts[i0];
        c0 = v.x; c1 = v.y; c2 = v.z; c3 = v.w;
    } else {
        if (i0 + 0 < N_NODES) c0 = counts[i0 + 0];
        if (i0 + 1 < N_NODES) c1 = counts[i0 + 1];
        if (i0 + 2 < N_NODES) c2 = counts[i0 + 2];
        if (i0 + 3 < N_NODES) c3 = counts[i0 + 3];
    }
    const int s = c0 + c1 + c2 + c3;
    t[tid] = s;
    __syncthreads();

    for (int d = 1; d < 256; d <<= 1) {
        int x = t[tid];
        int add = (tid >= d) ? t[tid - d] : 0;
        __syncthreads();
        t[tid] = x + add;
        __syncthreads();
    }
    const int excl = t[tid] - s;
    if (tid == 255) bsums[blockIdx.x] = t[255];

    const int e0 = excl;
    const int e1 = e0 + c0;
    const int e2 = e1 + c1;
    const int e3 = e2 + c2;
    if (i0 + 0 < N_NODES) off[i0 + 0] = e0;
    if (i0 + 1 < N_NODES) off[i0 + 1] = e1;
    if (i0 + 2 < N_NODES) off[i0 + 2] = e2;
    if (i0 + 3 < N_NODES) off[i0 + 3] = e3;
}

// ---------------------------------------------------------------------------
// CSR build step 2b: exclusive scan of block sums (single block).
// ---------------------------------------------------------------------------
__global__ __launch_bounds__(128) void gcn_scan2_kernel(int* __restrict__ bsums, int nb)
{
    __shared__ int t[128];
    const int tid = threadIdx.x;
    const int v = (tid < nb) ? bsums[tid] : 0;
    t[tid] = v;
    __syncthreads();
    for (int d = 1; d < 128; d <<= 1) {
        int x = t[tid];
        int add = (tid >= d) ? t[tid - d] : 0;
        __syncthreads();
        t[tid] = x + add;
        __syncthreads();
    }
    if (tid < nb) bsums[tid] = t[tid] - v;
}

// ---------------------------------------------------------------------------
// CSR build step 2c: add block offsets; init cursor = start offset.
// ---------------------------------------------------------------------------
__global__ __launch_bounds__(256) void gcn_scan3_kernel(
    const int* __restrict__ bsums, int* __restrict__ off, int* __restrict__ cursor)
{
    int i = blockIdx.x * 256 + threadIdx.x;
    if (i < N_NODES) {
        int o = off[i] + bsums[i >> 10];
        off[i] = o;
        cursor[i] = o;
    }
}

// ---------------------------------------------------------------------------
// CSR build step 3: scatter edges into row-sorted order as (col, val) pairs.
// ---------------------------------------------------------------------------
__global__ __launch_bounds__(256) void gcn_scatter_kernel(
    const int* __restrict__ rows, const int* __restrict__ cols,
    const float* __restrict__ vals, int* __restrict__ cursor,
    int2* __restrict__ edges)
{
    int e = blockIdx.x * 256 + threadIdx.x;
    if (e < N_EDGES) {
        int pos = atomicAdd(&cursor[rows[e]], 1);
        edges[pos] = make_int2(cols[e], __float_as_int(vals[e]));
    }
}

// ---------------------------------------------------------------------------
// Aggregate + ReLU: one 64-lane wave per node; support is bf16 -> one uint
// (2 cols) per lane per edge: 256 B coalesced gathers, L3-resident.
// ---------------------------------------------------------------------------
__global__ __launch_bounds__(256) void gcn_aggregate_kernel(
    const int* __restrict__ off, const int* __restrict__ ends,
    const int2* __restrict__ edges, const unsigned* __restrict__ supp2,
    float* __restrict__ out)
{
    const int node = blockIdx.x * 4 + (threadIdx.x >> 6);
    if (node >= N_NODES) return;
    const int lane = threadIdx.x & 63;

    const int start = off[node];
    const int end   = ends[node];

    float accx = 0.f, accy = 0.f;

    for (int base = start; base < end; base += 64) {
        int m = end - base;
        if (m > 64) m = 64;
        int2 e = edges[base + (lane < m ? lane : 0)];
        for (int j = 0; j < m; ++j) {
            const int      col = __shfl(e.x, j);
            const float    v   = __int_as_float(__shfl(e.y, j));
            const unsigned s   = supp2[(size_t)col * 64 + lane];
            accx = fmaf(v, __uint_as_float(s << 16), accx);
            accy = fmaf(v, __uint_as_float(s & 0xffff0000u), accy);
        }
    }

    float2 o;
    o.x = accx > 0.f ? accx : 0.f;
    o.y = accy > 0.f ? accy : 0.f;
    ((float2*)out)[(size_t)node * 64 + lane] = o;
}

extern "C" void kernel_launch(void* const* d_in, const int* in_sizes, int n_in,
                              void* d_out, int out_size, void* d_ws, size_t ws_size,
                              hipStream_t stream)
{
    const float* X    = (const float*)d_in[0];   // [N_NODES, D_IN]
    const float* W    = (const float*)d_in[1];   // [D_IN, D_OUT]
    const int*   rows = (const int*)  d_in[2];   // [N_EDGES]
    const int*   cols = (const int*)  d_in[3];   // [N_EDGES]
    const float* vals = (const float*)d_in[4];   // [N_EDGES]
    float* out = (float*)d_out;                  // [N_NODES, D_OUT]

    // ---- workspace layout (16B aligned) ----
    char* ws = (char*)d_ws;
    size_t p = 0;
    ushort* supp   = (ushort*)(ws + p); p += (size_t)N_NODES * D_OUT * 2;  // 25.6 MB
    int*    counts = (int*)   (ws + p); p += (size_t)N_NODES * 4;          // 0.4 MB
    int*    off    = (int*)   (ws + p); p += (size_t)N_NODES * 4;          // 0.4 MB
    int*    cursor = (int*)   (ws + p); p += (size_t)N_NODES * 4;          // 0.4 MB
    int*    bsums  = (int*)   (ws + p); p += 512;
    int2*   edges  = (int2*)  (ws + p); p += (size_t)N_EDGES * 8;          // 12.8 MB
    (void)ws_size;

    const int NB = (N_NODES + 1023) / 1024;  // 98 scan blocks

    // 1) support = bf16(X @ W)  (MFMA)
    gcn_gemm_mfma<<<(N_NODES + 127) / 128, 256, 0, stream>>>(X, W, supp);

    // 2) CSR build
    (void)hipMemsetAsync(counts, 0, (size_t)N_NODES * 4, stream);
    gcn_hist_kernel<<<(N_EDGES + 255) / 256, 256, 0, stream>>>(rows, counts);
    gcn_scan1_kernel<<<NB, 256, 0, stream>>>(counts, off, bsums);
    gcn_scan2_kernel<<<1, 128, 0, stream>>>(bsums, NB);
    gcn_scan3_kernel<<<(N_NODES + 255) / 256, 256, 0, stream>>>(bsums, off, cursor);
    gcn_scatter_kernel<<<(N_EDGES + 255) / 256, 256, 0, stream>>>(rows, cols, vals, cursor, edges);

    // 3) out = ReLU(A @ support)  — gather-reduce, no fp atomics
    gcn_aggregate_kernel<<<(N_NODES + 3) / 4, 256, 0, stream>>>(
        off, cursor, edges, (const unsigned*)supp, out);
}